// Round 2
// baseline (2113.662 us; speedup 1.0000x reference)
//
#include <hip/hip_runtime.h>
#include <cstdint>

typedef __attribute__((ext_vector_type(8))) short bf16x8;
typedef __attribute__((ext_vector_type(4))) float f32x4;

#define RSC 0.1f

__device__ __forceinline__ short f2bf(float f){
  union { float f; unsigned u; } v; v.f = f;
  unsigned r = v.u + 0x7FFFu + ((v.u >> 16) & 1u);
  return (short)(r >> 16);
}
__device__ __forceinline__ float bf2f(short h){
  union { unsigned u; float f; } v; v.u = ((unsigned)(unsigned short)h) << 16;
  return v.f;
}
__device__ __forceinline__ void gload16(const void* g, void* l){
  __builtin_amdgcn_global_load_lds(
    (const __attribute__((address_space(1))) unsigned int*)(uintptr_t)g,
    (__attribute__((address_space(3))) unsigned int*)(unsigned int)(uintptr_t)l,
    16, 0, 0);
}

// ---------------- weight fp32 -> bf16 ----------------
__global__ __launch_bounds__(256) void cvt_bf16(const float* __restrict__ s,
                                                short* __restrict__ d, int n){
  int i = (blockIdx.x*256 + threadIdx.x)*4;
  if (i >= n) return;
  float4 v = *(const float4*)&s[i];
  unsigned lo = (unsigned)(unsigned short)f2bf(v.x) | ((unsigned)(unsigned short)f2bf(v.y) << 16);
  unsigned hi = (unsigned)(unsigned short)f2bf(v.z) | ((unsigned)(unsigned short)f2bf(v.w) << 16);
  uint2 o; o.x = lo; o.y = hi;
  *(uint2*)&d[i] = o;
}

// ---------------- relative-position bias in MFMA D-fragment layout ----------------
// layout: [h][si][sj][lane] float4 ; value = rpb[((di+7)*15 + dj+7)*6 + h]
__global__ __launch_bounds__(64) void k_biasfrag(const float* __restrict__ rpb,
                                                 float* __restrict__ bfrag){
  int blk = blockIdx.x;            // h*16 + si*4 + sj  (96 blocks)
  int h = blk >> 4, si = (blk >> 2) & 3, sj = blk & 3;
  int lane = threadIdx.x;
  int g = lane >> 4, a = lane & 15;
  f32x4 v;
  #pragma unroll
  for (int r=0;r<4;r++){
    int row = si*16 + g*4 + r;     // query token n
    int col = sj*16 + a;           // key token m
    int di = (row>>3) - (col>>3) + 7;
    int dj = (row&7) - (col&7) + 7;
    v[r] = rpb[(di*15 + dj)*6 + h];
  }
  *(f32x4*)&bfrag[((long)blk*64 + lane)*4] = v;
}

// ---------------- K1: LN1 per-pixel stats + sum(m*r) per batch ----------------
__global__ __launch_bounds__(256) void k1_ln1(const float* __restrict__ x,
    float* __restrict__ m1, float* __restrict__ r1, float* __restrict__ M1){
  int idx = blockIdx.x*256 + threadIdx.x;       // 0..262143
  int b = idx >> 16, p = idx & 65535;
  const float* xp = x + (long)b*192*65536 + p;
  float s = 0.f, q = 0.f;
  #pragma unroll 8
  for (int c=0;c<192;c++){ float v = xp[(long)c*65536]; s += v; q += v*v; }
  float mean = s * (1.f/192.f);
  float var  = q * (1.f/192.f) - mean*mean;
  float rstd = rsqrtf(var + 1e-5f);
  m1[idx] = mean; r1[idx] = rstd;
  float mr = mean * rstd;
  mr += __shfl_xor(mr, 32, 64); mr += __shfl_xor(mr, 16, 64);
  mr += __shfl_xor(mr, 8, 64);  mr += __shfl_xor(mr, 4, 64);
  mr += __shfl_xor(mr, 2, 64);  mr += __shfl_xor(mr, 1, 64);
  if ((threadIdx.x & 63) == 0) atomicAdd(&M1[b], mr);
}

// ---------------- K2: pooled sums S1[b,c] = sum_p x*rstd ----------------
__global__ __launch_bounds__(256) void k2_pool(const float* __restrict__ x,
    const float* __restrict__ r1, float* __restrict__ pool){
  int bc = blockIdx.x;            // 0..767 = b*192+c
  int b = bc / 192;
  int p0 = blockIdx.y*2048 + threadIdx.x;
  const float* xp = x + (long)bc*65536;
  const float* rp = r1 + (long)b*65536;
  float s = 0.f;
  #pragma unroll
  for (int i=0;i<8;i++){ int p = p0 + i*256; s += xp[p]*rp[p]; }
  s += __shfl_xor(s, 32, 64); s += __shfl_xor(s, 16, 64);
  s += __shfl_xor(s, 8, 64);  s += __shfl_xor(s, 4, 64);
  s += __shfl_xor(s, 2, 64);  s += __shfl_xor(s, 1, 64);
  if ((threadIdx.x & 63) == 0) atomicAdd(&pool[bc], s);
}

// ---------------- K3: SE MLP -> y[b,c] = sigmoid(relu(pm@w1^T)@w2^T) ----------------
__global__ __launch_bounds__(192) void k3_se(const float* __restrict__ pool,
    const float* __restrict__ M1, const float* __restrict__ n1w, const float* __restrict__ n1b,
    const float* __restrict__ w1, const float* __restrict__ w2, float* __restrict__ y){
  __shared__ float pm[192];
  __shared__ float tv[12];
  int t = threadIdx.x;
  for (int b=0;b<4;b++){
    pm[t] = n1w[t]*(pool[b*192+t] - M1[b])*(1.f/65536.f) + n1b[t];
    __syncthreads();
    if (t < 12){
      float acc = 0.f;
      for (int c=0;c<192;c++) acc += pm[c]*w1[t*192+c];
      tv[t] = fmaxf(acc, 0.f);
    }
    __syncthreads();
    float z = 0.f;
    #pragma unroll
    for (int r=0;r<12;r++) z += tv[r]*w2[t*12+r];
    y[b*192+t] = 1.f/(1.f + __expf(-z));
    __syncthreads();
  }
}

// ---------------- K4: recompute x1, LN2, window-partition, write bf16 tokens (one batch) ----------------
__global__ __launch_bounds__(256) void k4_ln2win(const float* __restrict__ x,
    const float* __restrict__ m1, const float* __restrict__ r1, const float* __restrict__ y,
    const float* __restrict__ n1w, const float* __restrict__ n1b,
    const float* __restrict__ n2w, const float* __restrict__ n2b,
    short* __restrict__ xw, int b){
  __shared__ float xt[192*65];
  __shared__ float yl[192], w1l[192], b1l[192], w2l[192], b2l[192];
  __shared__ float ps[8*66];
  __shared__ float m2l[64], r2l[64];

  int win = blockIdx.x;                 // 0..1023 = wh*32 + ww (chunk-local)
  int wh = win >> 5, ww = win & 31;
  int t = threadIdx.x;
  if (t < 192){
    yl[t] = y[b*192+t]; w1l[t] = n1w[t]; b1l[t] = n1b[t]; w2l[t] = n2w[t]; b2l[t] = n2b[t];
  }
  __syncthreads();

  int tok = t & 63, csub = t >> 6;
  int wi = tok >> 3, wj = tok & 7;
  int p = (wh*8 + wi)*256 + ww*8 + wj;
  const float* xb = x + (long)b*192*65536 + p;
  float sm = m1[b*65536 + p], sr = r1[b*65536 + p];

  #pragma unroll 4
  for (int cb=0; cb<48; cb++){
    int c = cb*4 + csub;
    float v = xb[(long)c*65536];
    float x1 = ((v - sm)*sr*w1l[c] + b1l[c]) * yl[c] * RSC + v;
    xt[c*65 + tok] = x1;
  }
  __syncthreads();
  float s = 0.f, q = 0.f;
  #pragma unroll 8
  for (int k=0;k<48;k++){
    float v = xt[(csub*48 + k)*65 + tok];
    s += v; q += v*v;
  }
  ps[csub*66 + tok] = s;
  ps[(4+csub)*66 + tok] = q;
  __syncthreads();
  if (t < 64){
    float ss = ps[t] + ps[66+t] + ps[2*66+t] + ps[3*66+t];
    float qq = ps[4*66+t] + ps[5*66+t] + ps[6*66+t] + ps[7*66+t];
    float mean = ss*(1.f/192.f);
    float var  = qq*(1.f/192.f) - mean*mean;
    m2l[t] = mean; r2l[t] = rsqrtf(var + 1e-5f);
  }
  __syncthreads();
  int tok2 = t >> 2, seg = (t & 3)*48;
  long obase = ((long)win*64 + tok2)*192 + seg;
  float mm = m2l[tok2], rr = r2l[tok2];
  #pragma unroll
  for (int ch=0; ch<6; ch++){
    bf16x8 vec;
    #pragma unroll
    for (int e=0;e<8;e++){
      int c = seg + ch*8 + e;
      float v = (xt[c*65 + tok2] - mm)*rr*w2l[c] + b2l[c];
      vec[e] = f2bf(v);
    }
    *(bf16x8*)&xw[obase + ch*8] = vec;
  }
}

// ---------------- GEMM: out[M,N](bf16) = A[M,K](bf16) @ W[N,K]^T (+bias)(+gelu) ----------------
__global__ __launch_bounds__(256) void gemm_bt(
    const short* __restrict__ A, const short* __restrict__ Bw,
    const float* __restrict__ bias, short* __restrict__ out,
    int M, int N, int K, int epi){
  __shared__ short As[128*32];
  __shared__ short Bs[128*32];
  __shared__ short Es[4*64*72];

  unsigned flat = blockIdx.y * gridDim.x + blockIdx.x;
  unsigned tot  = gridDim.x * gridDim.y;       // always % 8 == 0 here
  unsigned id2  = (flat & 7u) * (tot >> 3) + (flat >> 3);   // XCD-contiguous slabs
  int bx = id2 % gridDim.x;
  int by = id2 / gridDim.x;

  int tid = threadIdx.x;
  int lane = tid & 63;
  int wid = __builtin_amdgcn_readfirstlane(tid >> 6);
  int g = lane >> 4, a = lane & 15;
  int wr = (wid >> 1) * 64;
  int wc = (wid & 1) * 64;

  long row0 = (long)by * 128;
  int  col0 = bx * 128;

  const f32x4 zz = {0.f,0.f,0.f,0.f};
  f32x4 acc[4][4];
  #pragma unroll
  for (int i=0;i<4;i++)
    #pragma unroll
    for (int j=0;j<4;j++) acc[i][j] = zz;

  const short* ga = A  + (row0 + wid*32 + (lane>>2)) * (long)K + (lane&3)*8;
  const short* gb = Bw + ((long)(col0 + wid*32 + (lane>>2))) * K + (lane&3)*8;
  short* la = &As[wid*32*32];
  short* lb = &Bs[wid*32*32];

  for (int k0 = 0; k0 < K; k0 += 32){
    gload16(ga + k0,        la);
    gload16(ga + k0 + 16*K, la + 16*32);
    gload16(gb + k0,        lb);
    gload16(gb + k0 + 16*K, lb + 16*32);
    __syncthreads();
    bf16x8 af[4], bfg[4];
    #pragma unroll
    for (int t=0;t<4;t++) af[t]  = *(const bf16x8*)&As[(wr + t*16 + a)*32 + g*8];
    #pragma unroll
    for (int t=0;t<4;t++) bfg[t] = *(const bf16x8*)&Bs[(wc + t*16 + a)*32 + g*8];
    #pragma unroll
    for (int i=0;i<4;i++)
      #pragma unroll
      for (int j=0;j<4;j++)
        acc[i][j] = __builtin_amdgcn_mfma_f32_16x16x32_bf16(af[i], bfg[j], acc[i][j], 0, 0, 0);
    __syncthreads();
  }

  float bv[4];
  #pragma unroll
  for (int j=0;j<4;j++){
    int cA = col0 + wc + j*16 + a;
    bv[j] = (epi >= 1) ? bias[cA < N ? cA : 0] : 0.f;
  }
  short* es = &Es[wid*64*72];
  #pragma unroll
  for (int i=0;i<4;i++)
    #pragma unroll
    for (int j=0;j<4;j++)
      #pragma unroll
      for (int r=0;r<4;r++){
        float v = acc[i][j][r] + bv[j];
        if (epi == 2) v = 0.5f*v*(1.f + erff(v*0.70710678118f));
        es[(i*16 + g*4 + r)*72 + j*16 + a] = f2bf(v);
      }
  // wave-private LDS region: compiler orders ds_write->ds_read via lgkmcnt
  if (col0 + wc < N){
    long ob = (row0 + wr + lane) * (long)N + col0 + wc;
    #pragma unroll
    for (int ch=0; ch<8; ch++)
      *(uint4*)&out[ob + ch*8] = *(const uint4*)&es[lane*72 + ch*8];
  }
}

// ---------------- window attention: one wave per (window, head), one batch chunk ----------------
__global__ __launch_bounds__(64) void attn_kernel(const short* __restrict__ qkv,
    const float* __restrict__ biasFrag, short* __restrict__ attOut){
  __shared__ short vlds[64*36];
  __shared__ short plds[64*72];
  __shared__ short olds[64*40];

  unsigned flat = blockIdx.x;
  unsigned tot  = gridDim.x;        // 6144 % 8 == 0
  unsigned id2  = (flat & 7u) * (tot >> 3) + (flat >> 3);
  int win = id2 / 6, h = id2 % 6;   // win chunk-local 0..1023
  int lane = threadIdx.x;
  int g = lane >> 4, a = lane & 15;
  long base = (long)win * 64 * 576;
  const short* qp = qkv + base + h*32;
  const short* kp = qkv + base + 192 + h*32;
  const short* vp = qkv + base + 384 + h*32;

  // stage V rows [64][32] -> vlds[64][36]
  #pragma unroll
  for (int it=0; it<8; it++){
    int idx = it*64 + lane;
    int m = idx >> 3, ch = idx & 7;
    *(uint2*)&vlds[m*36 + ch*4] = *(const uint2*)&vp[(long)m*576 + ch*4];
  }

  bf16x8 qf[4], kf[4];
  #pragma unroll
  for (int t=0;t<4;t++) qf[t] = *(const bf16x8*)&qp[(t*16+a)*576 + g*8];
  #pragma unroll
  for (int t=0;t<4;t++) kf[t] = *(const bf16x8*)&kp[(t*16+a)*576 + g*8];

  const f32x4 zz = {0.f,0.f,0.f,0.f};
  f32x4 s[4][4];
  #pragma unroll
  for (int i=0;i<4;i++)
    #pragma unroll
    for (int j=0;j<4;j++)
      s[i][j] = __builtin_amdgcn_mfma_f32_16x16x32_bf16(qf[i], kf[j], zz, 0, 0, 0);

  const float scale = 0.17677669529663687f;   // 1/sqrt(32)
  #pragma unroll
  for (int i=0;i<4;i++)
    #pragma unroll
    for (int j=0;j<4;j++){
      f32x4 bv = *(const f32x4*)&biasFrag[(((h*16 + i*4 + j)*64) + lane)*4];
      #pragma unroll
      for (int r=0;r<4;r++) s[i][j][r] = s[i][j][r]*scale + bv[r];
    }

  // row softmax (rows spread over 16 lanes sharing g)
  #pragma unroll
  for (int i=0;i<4;i++){
    #pragma unroll
    for (int r=0;r<4;r++){
      float mx = fmaxf(fmaxf(s[i][0][r], s[i][1][r]), fmaxf(s[i][2][r], s[i][3][r]));
      mx = fmaxf(mx, __shfl_xor(mx, 1, 64));
      mx = fmaxf(mx, __shfl_xor(mx, 2, 64));
      mx = fmaxf(mx, __shfl_xor(mx, 4, 64));
      mx = fmaxf(mx, __shfl_xor(mx, 8, 64));
      float e0 = __expf(s[i][0][r]-mx), e1 = __expf(s[i][1][r]-mx);
      float e2 = __expf(s[i][2][r]-mx), e3 = __expf(s[i][3][r]-mx);
      float sm = e0+e1+e2+e3;
      sm += __shfl_xor(sm, 1, 64); sm += __shfl_xor(sm, 2, 64);
      sm += __shfl_xor(sm, 4, 64); sm += __shfl_xor(sm, 8, 64);
      float inv = 1.f/sm;
      int rowl = i*16 + g*4 + r;
      plds[rowl*72 +      a] = f2bf(e0*inv);
      plds[rowl*72 + 16 + a] = f2bf(e1*inv);
      plds[rowl*72 + 32 + a] = f2bf(e2*inv);
      plds[rowl*72 + 48 + a] = f2bf(e3*inv);
    }
  }

  f32x4 o2[4][2];
  #pragma unroll
  for (int i=0;i<4;i++){ o2[i][0] = zz; o2[i][1] = zz; }
  #pragma unroll
  for (int km=0;km<2;km++){
    bf16x8 vb0, vb1;
    #pragma unroll
    for (int j=0;j<8;j++){
      int m = km*32 + g*8 + j;
      vb0[j] = vlds[m*36 + a];
      vb1[j] = vlds[m*36 + 16 + a];
    }
    #pragma unroll
    for (int oi=0;oi<4;oi++){
      bf16x8 pa = *(const bf16x8*)&plds[(oi*16 + a)*72 + km*32 + g*8];
      o2[oi][0] = __builtin_amdgcn_mfma_f32_16x16x32_bf16(pa, vb0, o2[oi][0], 0, 0, 0);
      o2[oi][1] = __builtin_amdgcn_mfma_f32_16x16x32_bf16(pa, vb1, o2[oi][1], 0, 0, 0);
    }
  }

  #pragma unroll
  for (int oi=0;oi<4;oi++)
    #pragma unroll
    for (int oj=0;oj<2;oj++)
      #pragma unroll
      for (int r=0;r<4;r++)
        olds[(oi*16 + g*4 + r)*40 + oj*16 + a] = f2bf(o2[oi][oj][r]);
  long ob = ((long)win*64 + lane)*192 + h*32;
  #pragma unroll
  for (int ch=0;ch<4;ch++)
    *(uint4*)&attOut[ob + ch*8] = *(const uint4*)&olds[lane*40 + ch*8];
}

// ---------------- LN3: 16 lanes per token (one batch chunk: 65536 tokens) ----------------
__global__ __launch_bounds__(256) void k_ln3(const short* __restrict__ po,
    const float* __restrict__ n3w, const float* __restrict__ n3b, short* __restrict__ oln){
  int t = threadIdx.x;
  int lane = t & 63, wv = t >> 6;
  int tok = blockIdx.x*16 + wv*4 + (lane >> 4);
  int sub = lane & 15;
  long base = (long)tok*192 + sub*12;
  const short* row = po + base;
  unsigned d[6];
  #pragma unroll
  for (int k=0;k<6;k++) d[k] = *(const unsigned*)&row[k*2];
  float v[12];
  #pragma unroll
  for (int k=0;k<6;k++){
    v[2*k]   = bf2f((short)(d[k] & 0xffffu));
    v[2*k+1] = bf2f((short)(d[k] >> 16));
  }
  float s = 0.f, q = 0.f;
  #pragma unroll
  for (int e=0;e<12;e++){ s += v[e]; q += v[e]*v[e]; }
  s += __shfl_xor(s, 1, 64); s += __shfl_xor(s, 2, 64);
  s += __shfl_xor(s, 4, 64); s += __shfl_xor(s, 8, 64);
  q += __shfl_xor(q, 1, 64); q += __shfl_xor(q, 2, 64);
  q += __shfl_xor(q, 4, 64); q += __shfl_xor(q, 8, 64);
  float mean = s*(1.f/192.f);
  float var  = q*(1.f/192.f) - mean*mean;
  float r = rsqrtf(var + 1e-5f);
  short* orow = oln + base;
  #pragma unroll
  for (int k=0;k<6;k++){
    int c0 = sub*12 + 2*k;
    float a0 = (v[2*k]   - mean)*r*n3w[c0]   + n3b[c0];
    float a1 = (v[2*k+1] - mean)*r*n3w[c0+1] + n3b[c0+1];
    unsigned o = (unsigned)(unsigned short)f2bf(a0) | ((unsigned)(unsigned short)f2bf(a1) << 16);
    *(unsigned*)&orow[k*2] = o;
  }
}

// ---------------- final: out = (oln + f2*RS)*RS + x1, un-window + transpose (one batch) ----------------
__global__ __launch_bounds__(256) void k8_final(const float* __restrict__ x,
    const float* __restrict__ m1, const float* __restrict__ r1, const float* __restrict__ y,
    const float* __restrict__ n1w, const float* __restrict__ n1b,
    const short* __restrict__ oln, const short* __restrict__ f2,
    float* __restrict__ out, int b){
  int c  = blockIdx.x;              // 0..191
  int hh = blockIdx.y;              // 0..255
  int wcol = threadIdx.x;
  int p = hh*256 + wcol;
  long xi = ((long)b*192 + c)*65536 + p;
  float xv = x[xi];
  float mm = m1[b*65536 + p], rr = r1[b*65536 + p];
  float yv = y[b*192 + c];
  int tok = ((hh>>3)*32 + (wcol>>3))*64 + (hh&7)*8 + (wcol&7);   // chunk-local
  float ov = bf2f(oln[(long)tok*192 + c]);
  float fv = bf2f(f2[(long)tok*192 + c]);
  float x1 = ((xv - mm)*rr*n1w[c] + n1b[c])*yv*RSC + xv;
  out[xi] = (ov + fv*RSC)*RSC + x1;
}

extern "C" void kernel_launch(void* const* d_in, const int* in_sizes, int n_in,
                              void* d_out, int out_size, void* d_ws, size_t ws_size,
                              hipStream_t stream){
  const float* x     = (const float*)d_in[0];
  const float* n1w   = (const float*)d_in[1];
  const float* n1b   = (const float*)d_in[2];
  const float* n2w   = (const float*)d_in[3];
  const float* n2b   = (const float*)d_in[4];
  const float* n3w   = (const float*)d_in[5];
  const float* n3b   = (const float*)d_in[6];
  const float* caw1  = (const float*)d_in[7];
  const float* caw2  = (const float*)d_in[8];
  const float* qkvw  = (const float*)d_in[9];
  const float* projw = (const float*)d_in[10];
  const float* projb = (const float*)d_in[11];
  const float* rpb   = (const float*)d_in[12];
  const float* fw1   = (const float*)d_in[13];
  const float* fb1   = (const float*)d_in[14];
  const float* fw2   = (const float*)d_in[15];
  const float* fb2   = (const float*)d_in[16];
  float* out = (float*)d_out;
  char* ws = (char*)d_ws;

  // ---- workspace plan (~208 MB total, chunked per batch) ----
  size_t off = 0;
  auto alloc = [&](size_t b){ size_t r = off; off += (b + 255) & ~(size_t)255; return r; };
  size_t oWQ  = alloc(640UL*192*2);          // qkv weight (640 rows: 5*128 tile pad)
  size_t oWP  = alloc(256UL*192*2);          // proj weight
  size_t oWF1 = alloc(768UL*192*2);          // ffn1 weight
  size_t oWF2 = alloc(256UL*768*2);          // ffn2 weight
  size_t oBF  = alloc(96UL*64*4*4);          // bias fragments
  size_t oPOOL= alloc(768*4 + 256);          // pool[768] then M1[4]
  size_t oY   = alloc(768*4);
  size_t oM   = alloc(262144UL*4);           // LN1 mean (all batches)
  size_t oR   = alloc(262144UL*4);           // LN1 rstd
  size_t oA   = alloc(65536UL*192*2);        // chunk: xw -> att -> oln   (24 MB)
  size_t oB   = alloc(65536UL*576*2);        // chunk: qkv -> proj_o -> f2 (72 MB)
  size_t oC   = alloc(65536UL*768*2);        // chunk: ffn hidden          (96 MB)

  short* WQ  = (short*)(ws + oWQ);
  short* WP  = (short*)(ws + oWP);
  short* WF1 = (short*)(ws + oWF1);
  short* WF2 = (short*)(ws + oWF2);
  float* BFr = (float*)(ws + oBF);
  float* POOL= (float*)(ws + oPOOL);
  float* M1  = POOL + 768;
  float* Y   = (float*)(ws + oY);
  float* Ms  = (float*)(ws + oM);
  float* Rs  = (float*)(ws + oR);
  short* XW  = (short*)(ws + oA);
  short* ATT = XW;
  short* OLN = XW;
  short* QKV = (short*)(ws + oB);
  short* PO  = QKV;
  short* F2  = QKV;
  short* Hb  = (short*)(ws + oC);

  hipMemsetAsync(ws + oPOOL, 0, 768*4 + 16, stream);

  cvt_bf16<<<108, 256, 0, stream>>>(qkvw,  WQ,  110592);
  cvt_bf16<<<36,  256, 0, stream>>>(projw, WP,  36864);
  cvt_bf16<<<144, 256, 0, stream>>>(fw1,   WF1, 147456);
  cvt_bf16<<<144, 256, 0, stream>>>(fw2,   WF2, 147456);
  k_biasfrag<<<96, 64, 0, stream>>>(rpb, BFr);

  k1_ln1<<<1024, 256, 0, stream>>>(x, Ms, Rs, M1);
  k2_pool<<<dim3(768, 32), 256, 0, stream>>>(x, Rs, POOL);
  k3_se<<<1, 192, 0, stream>>>(POOL, M1, n1w, n1b, caw1, caw2, Y);

  for (int b = 0; b < 4; b++){
    k4_ln2win<<<1024, 256, 0, stream>>>(x, Ms, Rs, Y, n1w, n1b, n2w, n2b, XW, b);
    gemm_bt<<<dim3(5, 512), 256, 0, stream>>>(XW, WQ, nullptr, QKV, 65536, 576, 192, 0);
    attn_kernel<<<6144, 64, 0, stream>>>(QKV, BFr, ATT);
    gemm_bt<<<dim3(2, 512), 256, 0, stream>>>(ATT, WP, projb, PO, 65536, 192, 192, 1);
    k_ln3<<<4096, 256, 0, stream>>>(PO, n3w, n3b, OLN);
    gemm_bt<<<dim3(6, 512), 256, 0, stream>>>(OLN, WF1, fb1, Hb, 65536, 768, 192, 2);
    gemm_bt<<<dim3(2, 512), 256, 0, stream>>>(Hb, WF2, fb2, F2, 65536, 192, 768, 1);
    k8_final<<<dim3(192, 256), 256, 0, stream>>>(x, Ms, Rs, Y, n1w, n1b, OLN, F2, out, b);
  }
}

// Round 5
// 1692.975 us; speedup vs baseline: 1.2485x; 1.2485x over previous
//
#include <hip/hip_runtime.h>
#include <cstdint>

typedef __attribute__((ext_vector_type(8))) short bf16x8;
typedef __attribute__((ext_vector_type(4))) float f32x4;

#define RSC 0.1f

__device__ __forceinline__ short f2bf(float f){
  union { float f; unsigned u; } v; v.f = f;
  unsigned r = v.u + 0x7FFFu + ((v.u >> 16) & 1u);
  return (short)(r >> 16);
}
__device__ __forceinline__ float bf2f(short h){
  union { unsigned u; float f; } v; v.u = ((unsigned)(unsigned short)h) << 16;
  return v.f;
}
__device__ __forceinline__ void gload16(const void* g, void* l){
  __builtin_amdgcn_global_load_lds(
    (const __attribute__((address_space(1))) unsigned int*)(uintptr_t)g,
    (__attribute__((address_space(3))) unsigned int*)(unsigned int)(uintptr_t)l,
    16, 0, 0);
}

// ---------------- weights fp32 -> bf16 (all four in one launch) ----------------
__global__ __launch_bounds__(256) void cvt_all(
    const float* __restrict__ s0, short* __restrict__ d0, int n0,
    const float* __restrict__ s1, short* __restrict__ d1, int n1,
    const float* __restrict__ s2, short* __restrict__ d2, int n2,
    const float* __restrict__ s3, short* __restrict__ d3, int n3){
  const float* s; short* d; int n;
  switch (blockIdx.y){
    case 0: s=s0; d=d0; n=n0; break;
    case 1: s=s1; d=d1; n=n1; break;
    case 2: s=s2; d=d2; n=n2; break;
    default: s=s3; d=d3; n=n3; break;
  }
  int i = (blockIdx.x*256 + threadIdx.x)*4;
  if (i >= n) return;
  float4 v = *(const float4*)&s[i];
  unsigned lo = (unsigned)(unsigned short)f2bf(v.x) | ((unsigned)(unsigned short)f2bf(v.y) << 16);
  unsigned hi = (unsigned)(unsigned short)f2bf(v.z) | ((unsigned)(unsigned short)f2bf(v.w) << 16);
  uint2 o; o.x = lo; o.y = hi;
  *(uint2*)&d[i] = o;
}

// ---------------- relative-position bias in MFMA D-fragment layout ----------------
__global__ __launch_bounds__(64) void k_biasfrag(const float* __restrict__ rpb,
                                                 float* __restrict__ bfrag){
  int blk = blockIdx.x;            // h*16 + si*4 + sj  (96 blocks)
  int h = blk >> 4, si = (blk >> 2) & 3, sj = blk & 3;
  int lane = threadIdx.x;
  int g = lane >> 4, a = lane & 15;
  f32x4 v;
  #pragma unroll
  for (int r=0;r<4;r++){
    int row = si*16 + g*4 + r;
    int col = sj*16 + a;
    int di = (row>>3) - (col>>3) + 7;
    int dj = (row&7) - (col&7) + 7;
    v[r] = rpb[(di*15 + dj)*6 + h];
  }
  *(f32x4*)&bfrag[((long)blk*64 + lane)*4] = v;
}

// ---------------- K1: LN1 per-pixel stats + sum(m*r) per batch ----------------
__global__ __launch_bounds__(256) void k1_ln1(const float* __restrict__ x,
    float* __restrict__ m1, float* __restrict__ r1, float* __restrict__ M1){
  int idx = blockIdx.x*256 + threadIdx.x;
  int b = idx >> 16, p = idx & 65535;
  const float* xp = x + (long)b*192*65536 + p;
  float s = 0.f, q = 0.f;
  #pragma unroll 8
  for (int c=0;c<192;c++){ float v = xp[(long)c*65536]; s += v; q += v*v; }
  float mean = s * (1.f/192.f);
  float var  = q * (1.f/192.f) - mean*mean;
  float rstd = rsqrtf(var + 1e-5f);
  m1[idx] = mean; r1[idx] = rstd;
  float mr = mean * rstd;
  mr += __shfl_xor(mr, 32, 64); mr += __shfl_xor(mr, 16, 64);
  mr += __shfl_xor(mr, 8, 64);  mr += __shfl_xor(mr, 4, 64);
  mr += __shfl_xor(mr, 2, 64);  mr += __shfl_xor(mr, 1, 64);
  if ((threadIdx.x & 63) == 0) atomicAdd(&M1[b], mr);
}

// ---------------- K2: pooled sums S1[b,c] = sum_p x*rstd ----------------
__global__ __launch_bounds__(256) void k2_pool(const float* __restrict__ x,
    const float* __restrict__ r1, float* __restrict__ pool){
  int bc = blockIdx.x;
  int b = bc / 192;
  int p0 = blockIdx.y*2048 + threadIdx.x;
  const float* xp = x + (long)bc*65536;
  const float* rp = r1 + (long)b*65536;
  float s = 0.f;
  #pragma unroll
  for (int i=0;i<8;i++){ int p = p0 + i*256; s += xp[p]*rp[p]; }
  s += __shfl_xor(s, 32, 64); s += __shfl_xor(s, 16, 64);
  s += __shfl_xor(s, 8, 64);  s += __shfl_xor(s, 4, 64);
  s += __shfl_xor(s, 2, 64);  s += __shfl_xor(s, 1, 64);
  if ((threadIdx.x & 63) == 0) atomicAdd(&pool[bc], s);
}

// ---------------- K3: SE MLP ----------------
__global__ __launch_bounds__(192) void k3_se(const float* __restrict__ pool,
    const float* __restrict__ M1, const float* __restrict__ n1w, const float* __restrict__ n1b,
    const float* __restrict__ w1, const float* __restrict__ w2, float* __restrict__ y){
  __shared__ float pm[192];
  __shared__ float tv[12];
  int t = threadIdx.x;
  for (int b=0;b<4;b++){
    pm[t] = n1w[t]*(pool[b*192+t] - M1[b])*(1.f/65536.f) + n1b[t];
    __syncthreads();
    if (t < 12){
      float acc = 0.f;
      for (int c=0;c<192;c++) acc += pm[c]*w1[t*192+c];
      tv[t] = fmaxf(acc, 0.f);
    }
    __syncthreads();
    float z = 0.f;
    #pragma unroll
    for (int r=0;r<12;r++) z += tv[r]*w2[t*12+r];
    y[b*192+t] = 1.f/(1.f + __expf(-z));
    __syncthreads();
  }
}

// ---------------- K4: recompute x1, LN2, window-partition, write bf16 tokens (one batch) ----------------
__global__ __launch_bounds__(256) void k4_ln2win(const float* __restrict__ x,
    const float* __restrict__ m1, const float* __restrict__ r1, const float* __restrict__ y,
    const float* __restrict__ n1w, const float* __restrict__ n1b,
    const float* __restrict__ n2w, const float* __restrict__ n2b,
    short* __restrict__ xw, int b){
  __shared__ float xt[192*65];
  __shared__ float yl[192], w1l[192], b1l[192], w2l[192], b2l[192];
  __shared__ float ps[8*66];
  __shared__ float m2l[64], r2l[64];

  int win = blockIdx.x;
  int wh = win >> 5, ww = win & 31;
  int t = threadIdx.x;
  if (t < 192){
    yl[t] = y[b*192+t]; w1l[t] = n1w[t]; b1l[t] = n1b[t]; w2l[t] = n2w[t]; b2l[t] = n2b[t];
  }
  __syncthreads();

  int tok = t & 63, csub = t >> 6;
  int wi = tok >> 3, wj = tok & 7;
  int p = (wh*8 + wi)*256 + ww*8 + wj;
  const float* xb = x + (long)b*192*65536 + p;
  float sm = m1[b*65536 + p], sr = r1[b*65536 + p];

  #pragma unroll 4
  for (int cb=0; cb<48; cb++){
    int c = cb*4 + csub;
    float v = xb[(long)c*65536];
    float x1 = ((v - sm)*sr*w1l[c] + b1l[c]) * yl[c] * RSC + v;
    xt[c*65 + tok] = x1;
  }
  __syncthreads();
  float s = 0.f, q = 0.f;
  #pragma unroll 8
  for (int k=0;k<48;k++){
    float v = xt[(csub*48 + k)*65 + tok];
    s += v; q += v*v;
  }
  ps[csub*66 + tok] = s;
  ps[(4+csub)*66 + tok] = q;
  __syncthreads();
  if (t < 64){
    float ss = ps[t] + ps[66+t] + ps[2*66+t] + ps[3*66+t];
    float qq = ps[4*66+t] + ps[5*66+t] + ps[6*66+t] + ps[7*66+t];
    float mean = ss*(1.f/192.f);
    float var  = qq*(1.f/192.f) - mean*mean;
    m2l[t] = mean; r2l[t] = rsqrtf(var + 1e-5f);
  }
  __syncthreads();
  int tok2 = t >> 2, seg = (t & 3)*48;
  long obase = ((long)win*64 + tok2)*192 + seg;
  float mm = m2l[tok2], rr = r2l[tok2];
  #pragma unroll
  for (int ch=0; ch<6; ch++){
    bf16x8 vec;
    #pragma unroll
    for (int e=0;e<8;e++){
      int c = seg + ch*8 + e;
      float v = (xt[c*65 + tok2] - mm)*rr*w2l[c] + b2l[c];
      vec[e] = f2bf(v);
    }
    *(bf16x8*)&xw[obase + ch*8] = vec;
  }
}

// ---------------- GEMM: out[M,N](bf16) = A[M,K](bf16) @ W[N,K]^T (+bias)(+gelu) ----------------
__global__ __launch_bounds__(256) void gemm_bt(
    const short* __restrict__ A, const short* __restrict__ Bw,
    const float* __restrict__ bias, short* __restrict__ out,
    int M, int N, int K, int epi){
  __shared__ short As[128*32];
  __shared__ short Bs[128*32];
  __shared__ short Es[4*64*72];

  unsigned flat = blockIdx.y * gridDim.x + blockIdx.x;
  unsigned tot  = gridDim.x * gridDim.y;
  unsigned id2  = (flat & 7u) * (tot >> 3) + (flat >> 3);
  int bx = id2 % gridDim.x;
  int by = id2 / gridDim.x;

  int tid = threadIdx.x;
  int lane = tid & 63;
  int wid = __builtin_amdgcn_readfirstlane(tid >> 6);
  int g = lane >> 4, a = lane & 15;
  int wr = (wid >> 1) * 64;
  int wc = (wid & 1) * 64;

  long row0 = (long)by * 128;
  int  col0 = bx * 128;

  const f32x4 zz = {0.f,0.f,0.f,0.f};
  f32x4 acc[4][4];
  #pragma unroll
  for (int i=0;i<4;i++)
    #pragma unroll
    for (int j=0;j<4;j++) acc[i][j] = zz;

  const short* ga = A  + (row0 + wid*32 + (lane>>2)) * (long)K + (lane&3)*8;
  const short* gb = Bw + ((long)(col0 + wid*32 + (lane>>2))) * K + (lane&3)*8;
  short* la = &As[wid*32*32];
  short* lb = &Bs[wid*32*32];

  for (int k0 = 0; k0 < K; k0 += 32){
    gload16(ga + k0,        la);
    gload16(ga + k0 + 16*K, la + 16*32);
    gload16(gb + k0,        lb);
    gload16(gb + k0 + 16*K, lb + 16*32);
    __syncthreads();
    bf16x8 af[4], bfg[4];
    #pragma unroll
    for (int t=0;t<4;t++) af[t]  = *(const bf16x8*)&As[(wr + t*16 + a)*32 + g*8];
    #pragma unroll
    for (int t=0;t<4;t++) bfg[t] = *(const bf16x8*)&Bs[(wc + t*16 + a)*32 + g*8];
    #pragma unroll
    for (int i=0;i<4;i++)
      #pragma unroll
      for (int j=0;j<4;j++)
        acc[i][j] = __builtin_amdgcn_mfma_f32_16x16x32_bf16(af[i], bfg[j], acc[i][j], 0, 0, 0);
    __syncthreads();
  }

  float bv[4];
  #pragma unroll
  for (int j=0;j<4;j++){
    int cA = col0 + wc + j*16 + a;
    bv[j] = (epi >= 1) ? bias[cA < N ? cA : 0] : 0.f;
  }
  short* es = &Es[wid*64*72];
  #pragma unroll
  for (int i=0;i<4;i++)
    #pragma unroll
    for (int j=0;j<4;j++)
      #pragma unroll
      for (int r=0;r<4;r++){
        float v = acc[i][j][r] + bv[j];
        if (epi == 2) v = 0.5f*v*(1.f + erff(v*0.70710678118f));
        es[(i*16 + g*4 + r)*72 + j*16 + a] = f2bf(v);
      }
  if (col0 + wc < N){
    long ob = (row0 + wr + lane) * (long)N + col0 + wc;
    #pragma unroll
    for (int ch=0; ch<8; ch++)
      *(uint4*)&out[ob + ch*8] = *(const uint4*)&es[lane*72 + ch*8];
  }
}

// ---------------- window attention: one wave per (window, head) ----------------
__global__ __launch_bounds__(64) void attn_kernel(const short* __restrict__ qkv,
    const float* __restrict__ biasFrag, short* __restrict__ attOut){
  __shared__ short vlds[64*36];
  __shared__ short plds[64*72];
  __shared__ short olds[64*40];

  unsigned flat = blockIdx.x;
  unsigned tot  = gridDim.x;
  unsigned id2  = (flat & 7u) * (tot >> 3) + (flat >> 3);
  int win = id2 / 6, h = id2 % 6;
  int lane = threadIdx.x;
  int g = lane >> 4, a = lane & 15;
  long base = (long)win * 64 * 576;
  const short* qp = qkv + base + h*32;
  const short* kp = qkv + base + 192 + h*32;
  const short* vp = qkv + base + 384 + h*32;

  #pragma unroll
  for (int it=0; it<8; it++){
    int idx = it*64 + lane;
    int m = idx >> 3, ch = idx & 7;
    *(uint2*)&vlds[m*36 + ch*4] = *(const uint2*)&vp[(long)m*576 + ch*4];
  }

  bf16x8 qf[4], kf[4];
  #pragma unroll
  for (int t=0;t<4;t++) qf[t] = *(const bf16x8*)&qp[(t*16+a)*576 + g*8];
  #pragma unroll
  for (int t=0;t<4;t++) kf[t] = *(const bf16x8*)&kp[(t*16+a)*576 + g*8];

  const f32x4 zz = {0.f,0.f,0.f,0.f};
  f32x4 s[4][4];
  #pragma unroll
  for (int i=0;i<4;i++)
    #pragma unroll
    for (int j=0;j<4;j++)
      s[i][j] = __builtin_amdgcn_mfma_f32_16x16x32_bf16(qf[i], kf[j], zz, 0, 0, 0);

  const float scale = 0.17677669529663687f;
  #pragma unroll
  for (int i=0;i<4;i++)
    #pragma unroll
    for (int j=0;j<4;j++){
      f32x4 bv = *(const f32x4*)&biasFrag[(((h*16 + i*4 + j)*64) + lane)*4];
      #pragma unroll
      for (int r=0;r<4;r++) s[i][j][r] = s[i][j][r]*scale + bv[r];
    }

  #pragma unroll
  for (int i=0;i<4;i++){
    #pragma unroll
    for (int r=0;r<4;r++){
      float mx = fmaxf(fmaxf(s[i][0][r], s[i][1][r]), fmaxf(s[i][2][r], s[i][3][r]));
      mx = fmaxf(mx, __shfl_xor(mx, 1, 64));
      mx = fmaxf(mx, __shfl_xor(mx, 2, 64));
      mx = fmaxf(mx, __shfl_xor(mx, 4, 64));
      mx = fmaxf(mx, __shfl_xor(mx, 8, 64));
      float e0 = __expf(s[i][0][r]-mx), e1 = __expf(s[i][1][r]-mx);
      float e2 = __expf(s[i][2][r]-mx), e3 = __expf(s[i][3][r]-mx);
      float sm = e0+e1+e2+e3;
      sm += __shfl_xor(sm, 1, 64); sm += __shfl_xor(sm, 2, 64);
      sm += __shfl_xor(sm, 4, 64); sm += __shfl_xor(sm, 8, 64);
      float inv = 1.f/sm;
      int rowl = i*16 + g*4 + r;
      plds[rowl*72 +      a] = f2bf(e0*inv);
      plds[rowl*72 + 16 + a] = f2bf(e1*inv);
      plds[rowl*72 + 32 + a] = f2bf(e2*inv);
      plds[rowl*72 + 48 + a] = f2bf(e3*inv);
    }
  }

  f32x4 o2[4][2];
  #pragma unroll
  for (int i=0;i<4;i++){ o2[i][0] = zz; o2[i][1] = zz; }
  #pragma unroll
  for (int km=0;km<2;km++){
    bf16x8 vb0, vb1;
    #pragma unroll
    for (int j=0;j<8;j++){
      int m = km*32 + g*8 + j;
      vb0[j] = vlds[m*36 + a];
      vb1[j] = vlds[m*36 + 16 + a];
    }
    #pragma unroll
    for (int oi=0;oi<4;oi++){
      bf16x8 pa = *(const bf16x8*)&plds[(oi*16 + a)*72 + km*32 + g*8];
      o2[oi][0] = __builtin_amdgcn_mfma_f32_16x16x32_bf16(pa, vb0, o2[oi][0], 0, 0, 0);
      o2[oi][1] = __builtin_amdgcn_mfma_f32_16x16x32_bf16(pa, vb1, o2[oi][1], 0, 0, 0);
    }
  }

  #pragma unroll
  for (int oi=0;oi<4;oi++)
    #pragma unroll
    for (int oj=0;oj<2;oj++)
      #pragma unroll
      for (int r=0;r<4;r++)
        olds[(oi*16 + g*4 + r)*40 + oj*16 + a] = f2bf(o2[oi][oj][r]);
  long ob = ((long)win*64 + lane)*192 + h*32;
  #pragma unroll
  for (int ch=0;ch<4;ch++)
    *(uint4*)&attOut[ob + ch*8] = *(const uint4*)&olds[lane*40 + ch*8];
}

// ---------------- LN3: 16 lanes per token ----------------
__global__ __launch_bounds__(256) void k_ln3(const short* __restrict__ po,
    const float* __restrict__ n3w, const float* __restrict__ n3b, short* __restrict__ oln){
  int t = threadIdx.x;
  int lane = t & 63, wv = t >> 6;
  int tok = blockIdx.x*16 + wv*4 + (lane >> 4);
  int sub = lane & 15;
  long base = (long)tok*192 + sub*12;
  const short* row = po + base;
  unsigned d[6];
  #pragma unroll
  for (int k=0;k<6;k++) d[k] = *(const unsigned*)&row[k*2];
  float v[12];
  #pragma unroll
  for (int k=0;k<6;k++){
    v[2*k]   = bf2f((short)(d[k] & 0xffffu));
    v[2*k+1] = bf2f((short)(d[k] >> 16));
  }
  float s = 0.f, q = 0.f;
  #pragma unroll
  for (int e=0;e<12;e++){ s += v[e]; q += v[e]*v[e]; }
  s += __shfl_xor(s, 1, 64); s += __shfl_xor(s, 2, 64);
  s += __shfl_xor(s, 4, 64); s += __shfl_xor(s, 8, 64);
  q += __shfl_xor(q, 1, 64); q += __shfl_xor(q, 2, 64);
  q += __shfl_xor(q, 4, 64); q += __shfl_xor(q, 8, 64);
  float mean = s*(1.f/192.f);
  float var  = q*(1.f/192.f) - mean*mean;
  float r = rsqrtf(var + 1e-5f);
  short* orow = oln + base;
  #pragma unroll
  for (int k=0;k<6;k++){
    int c0 = sub*12 + 2*k;
    float a0 = (v[2*k]   - mean)*r*n3w[c0]   + n3b[c0];
    float a1 = (v[2*k+1] - mean)*r*n3w[c0+1] + n3b[c0+1];
    unsigned o = (unsigned)(unsigned short)f2bf(a0) | ((unsigned)(unsigned short)f2bf(a1) << 16);
    *(unsigned*)&orow[k*2] = o;
  }
}

// ---------------- final: LDS-transposed residual merge (one batch) ----------------
// block: one image row (256 px) x 32 channels. Stage oln/f2 row-major coalesced,
// read back column-wise from LDS, fully-coalesced x-read + out-write.
__global__ __launch_bounds__(256) void k8_final(const float* __restrict__ x,
    const float* __restrict__ m1, const float* __restrict__ r1, const float* __restrict__ y,
    const float* __restrict__ n1w, const float* __restrict__ n1b,
    const short* __restrict__ oln, const short* __restrict__ f2,
    float* __restrict__ out, int b){
  __shared__ short so[256*36];     // [w][32ch], pad 4 shorts (72B rows)
  __shared__ short sf[256*36];
  __shared__ float smm[256], srr[256];

  int row = blockIdx.x;            // image row = wh*8 + wi
  int wh = row >> 3, wi = row & 7;
  int c0 = blockIdx.y * 32;
  int t  = threadIdx.x;

  smm[t] = m1[b*65536 + row*256 + t];
  srr[t] = r1[b*65536 + row*256 + t];

  // stage: 32 rows/pass, 8 lanes/row (8B each), 8 passes
  int rsub = t >> 3;               // 0..31
  int lw   = t & 7;                // 0..7
  #pragma unroll
  for (int pass=0; pass<8; pass++){
    int rw  = pass*32 + rsub;      // LDS row == pixel w
    int tok = wh*2048 + (rw>>3)*64 + wi*8 + (rw&7);
    long gi = (long)tok*192 + c0 + lw*4;     // shorts
    *(uint2*)&so[rw*36 + lw*4] = *(const uint2*)&oln[gi];
    *(uint2*)&sf[rw*36 + lw*4] = *(const uint2*)&f2[gi];
  }
  __syncthreads();

  float mm = smm[t], rr = srr[t];
  long xbase = ((long)b*192 + c0)*65536 + row*256 + t;
  #pragma unroll 4
  for (int ci=0; ci<32; ci++){
    int c = c0 + ci;
    float xv = x[xbase + (long)ci*65536];
    float ov = bf2f(so[t*36 + ci]);
    float fv = bf2f(sf[t*36 + ci]);
    float x1 = ((xv - mm)*rr*n1w[c] + n1b[c]) * y[b*192 + c] * RSC + xv;
    out[xbase + (long)ci*65536] = (ov + fv*RSC)*RSC + x1;
  }
}

extern "C" void kernel_launch(void* const* d_in, const int* in_sizes, int n_in,
                              void* d_out, int out_size, void* d_ws, size_t ws_size,
                              hipStream_t stream){
  const float* x     = (const float*)d_in[0];
  const float* n1w   = (const float*)d_in[1];
  const float* n1b   = (const float*)d_in[2];
  const float* n2w   = (const float*)d_in[3];
  const float* n2b   = (const float*)d_in[4];
  const float* n3w   = (const float*)d_in[5];
  const float* n3b   = (const float*)d_in[6];
  const float* caw1  = (const float*)d_in[7];
  const float* caw2  = (const float*)d_in[8];
  const float* qkvw  = (const float*)d_in[9];
  const float* projw = (const float*)d_in[10];
  const float* projb = (const float*)d_in[11];
  const float* rpb   = (const float*)d_in[12];
  const float* fw1   = (const float*)d_in[13];
  const float* fb1   = (const float*)d_in[14];
  const float* fw2   = (const float*)d_in[15];
  const float* fb2   = (const float*)d_in[16];
  float* out = (float*)d_out;
  char* ws = (char*)d_ws;

  size_t off = 0;
  auto alloc = [&](size_t b){ size_t r = off; off += (b + 255) & ~(size_t)255; return r; };
  size_t oWQ  = alloc(640UL*192*2);
  size_t oWP  = alloc(256UL*192*2);
  size_t oWF1 = alloc(768UL*192*2);
  size_t oWF2 = alloc(256UL*768*2);
  size_t oBF  = alloc(96UL*64*4*4);
  size_t oPOOL= alloc(768*4 + 256);
  size_t oY   = alloc(768*4);
  size_t oM   = alloc(262144UL*4);
  size_t oR   = alloc(262144UL*4);
  size_t oA   = alloc(65536UL*192*2);
  size_t oB   = alloc(65536UL*576*2);
  size_t oC   = alloc(65536UL*768*2);

  short* WQ  = (short*)(ws + oWQ);
  short* WP  = (short*)(ws + oWP);
  short* WF1 = (short*)(ws + oWF1);
  short* WF2 = (short*)(ws + oWF2);
  float* BFr = (float*)(ws + oBF);
  float* POOL= (float*)(ws + oPOOL);
  float* M1  = POOL + 768;
  float* Y   = (float*)(ws + oY);
  float* Ms  = (float*)(ws + oM);
  float* Rs  = (float*)(ws + oR);
  short* XW  = (short*)(ws + oA);
  short* ATT = XW;
  short* OLN = XW;
  short* QKV = (short*)(ws + oB);
  short* PO  = QKV;
  short* F2  = QKV;
  short* Hb  = (short*)(ws + oC);

  hipMemsetAsync(ws + oPOOL, 0, 768*4 + 16, stream);

  cvt_all<<<dim3(144, 4), 256, 0, stream>>>(qkvw, WQ, 110592, projw, WP, 36864,
                                            fw1, WF1, 147456, fw2, WF2, 147456);
  k_biasfrag<<<96, 64, 0, stream>>>(rpb, BFr);

  k1_ln1<<<1024, 256, 0, stream>>>(x, Ms, Rs, M1);
  k2_pool<<<dim3(768, 32), 256, 0, stream>>>(x, Rs, POOL);
  k3_se<<<1, 192, 0, stream>>>(POOL, M1, n1w, n1b, caw1, caw2, Y);

  for (int b = 0; b < 4; b++){
    k4_ln2win<<<1024, 256, 0, stream>>>(x, Ms, Rs, Y, n1w, n1b, n2w, n2b, XW, b);
    gemm_bt<<<dim3(5, 512), 256, 0, stream>>>(XW, WQ, nullptr, QKV, 65536, 576, 192, 0);
    attn_kernel<<<6144, 64, 0, stream>>>(QKV, BFr, ATT);
    gemm_bt<<<dim3(2, 512), 256, 0, stream>>>(ATT, WP, projb, PO, 65536, 192, 192, 1);
    k_ln3<<<4096, 256, 0, stream>>>(PO, n3w, n3b, OLN);
    gemm_bt<<<dim3(6, 512), 256, 0, stream>>>(OLN, WF1, fb1, Hb, 65536, 768, 192, 2);
    gemm_bt<<<dim3(2, 512), 256, 0, stream>>>(Hb, WF2, fb2, F2, 65536, 192, 768, 1);
    k8_final<<<dim3(256, 6), 256, 0, stream>>>(x, Ms, Rs, Y, n1w, n1b, OLN, F2, out, b);
  }
}

// Round 6
// 1650.253 us; speedup vs baseline: 1.2808x; 1.0259x over previous
//
#include <hip/hip_runtime.h>
#include <cstdint>

typedef __attribute__((ext_vector_type(8))) short bf16x8;
typedef __attribute__((ext_vector_type(4))) float f32x4;

#define RSC 0.1f

__device__ __forceinline__ short f2bf(float f){
  union { float f; unsigned u; } v; v.f = f;
  unsigned r = v.u + 0x7FFFu + ((v.u >> 16) & 1u);
  return (short)(r >> 16);
}
__device__ __forceinline__ float bf2f(short h){
  union { unsigned u; float f; } v; v.u = ((unsigned)(unsigned short)h) << 16;
  return v.f;
}
__device__ __forceinline__ void gload16(const void* g, void* l){
  __builtin_amdgcn_global_load_lds(
    (const __attribute__((address_space(1))) unsigned int*)(uintptr_t)g,
    (__attribute__((address_space(3))) unsigned int*)(unsigned int)(uintptr_t)l,
    16, 0, 0);
}

// ---------------- weights fp32 -> bf16 (all four in one launch) ----------------
__global__ __launch_bounds__(256) void cvt_all(
    const float* __restrict__ s0, short* __restrict__ d0, int n0,
    const float* __restrict__ s1, short* __restrict__ d1, int n1,
    const float* __restrict__ s2, short* __restrict__ d2, int n2,
    const float* __restrict__ s3, short* __restrict__ d3, int n3){
  const float* s; short* d; int n;
  switch (blockIdx.y){
    case 0: s=s0; d=d0; n=n0; break;
    case 1: s=s1; d=d1; n=n1; break;
    case 2: s=s2; d=d2; n=n2; break;
    default: s=s3; d=d3; n=n3; break;
  }
  int i = (blockIdx.x*256 + threadIdx.x)*4;
  if (i >= n) return;
  float4 v = *(const float4*)&s[i];
  unsigned lo = (unsigned)(unsigned short)f2bf(v.x) | ((unsigned)(unsigned short)f2bf(v.y) << 16);
  unsigned hi = (unsigned)(unsigned short)f2bf(v.z) | ((unsigned)(unsigned short)f2bf(v.w) << 16);
  uint2 o; o.x = lo; o.y = hi;
  *(uint2*)&d[i] = o;
}

// ---------------- relative-position bias in MFMA D-fragment layout ----------------
__global__ __launch_bounds__(64) void k_biasfrag(const float* __restrict__ rpb,
                                                 float* __restrict__ bfrag){
  int blk = blockIdx.x;            // h*16 + si*4 + sj  (96 blocks)
  int h = blk >> 4, si = (blk >> 2) & 3, sj = blk & 3;
  int lane = threadIdx.x;
  int g = lane >> 4, a = lane & 15;
  f32x4 v;
  #pragma unroll
  for (int r=0;r<4;r++){
    int row = si*16 + g*4 + r;
    int col = sj*16 + a;
    int di = (row>>3) - (col>>3) + 7;
    int dj = (row&7) - (col&7) + 7;
    v[r] = rpb[(di*15 + dj)*6 + h];
  }
  *(f32x4*)&bfrag[((long)blk*64 + lane)*4] = v;
}

// ---------------- K12: fused LN1 stats + channel pool ----------------
// Phase 1: per-pixel mean/rstd over 192 channels (coalesced; one HBM pass).
// Phase 2: per-wave 48-channel slice re-read (block footprint 196KB -> mostly L3)
//          accumulating pool[b,c] = sum_p x*rstd via wave-reduce + atomicAdd.
__global__ __launch_bounds__(256) void k12_ln1pool(const float* __restrict__ x,
    float* __restrict__ m1, float* __restrict__ r1, float* __restrict__ M1,
    float* __restrict__ pool){
  int idx = blockIdx.x*256 + threadIdx.x;
  int b = idx >> 16, p = idx & 65535;
  const float* xp = x + (long)b*192*65536 + p;
  float s = 0.f, q = 0.f;
  #pragma unroll 8
  for (int c=0;c<192;c++){ float v = xp[(long)c*65536]; s += v; q += v*v; }
  float mean = s * (1.f/192.f);
  float var  = q * (1.f/192.f) - mean*mean;
  float rstd = rsqrtf(var + 1e-5f);
  m1[idx] = mean; r1[idx] = rstd;
  float mr = mean * rstd;
  mr += __shfl_xor(mr, 32, 64); mr += __shfl_xor(mr, 16, 64);
  mr += __shfl_xor(mr, 8, 64);  mr += __shfl_xor(mr, 4, 64);
  mr += __shfl_xor(mr, 2, 64);  mr += __shfl_xor(mr, 1, 64);
  if ((threadIdx.x & 63) == 0) atomicAdd(&M1[b], mr);

  // phase 2: wave w owns channels [w*48, w*48+48)
  int w = threadIdx.x >> 6;
  #pragma unroll 4
  for (int cc=0; cc<48; cc++){
    int c = w*48 + cc;
    float v = xp[(long)c*65536] * rstd;
    v += __shfl_xor(v, 32, 64); v += __shfl_xor(v, 16, 64);
    v += __shfl_xor(v, 8, 64);  v += __shfl_xor(v, 4, 64);
    v += __shfl_xor(v, 2, 64);  v += __shfl_xor(v, 1, 64);
    if ((threadIdx.x & 63) == 0) atomicAdd(&pool[b*192 + c], v);
  }
}

// ---------------- K3: SE MLP ----------------
__global__ __launch_bounds__(192) void k3_se(const float* __restrict__ pool,
    const float* __restrict__ M1, const float* __restrict__ n1w, const float* __restrict__ n1b,
    const float* __restrict__ w1, const float* __restrict__ w2, float* __restrict__ y){
  __shared__ float pm[192];
  __shared__ float tv[12];
  int t = threadIdx.x;
  for (int b=0;b<4;b++){
    pm[t] = n1w[t]*(pool[b*192+t] - M1[b])*(1.f/65536.f) + n1b[t];
    __syncthreads();
    if (t < 12){
      float acc = 0.f;
      for (int c=0;c<192;c++) acc += pm[c]*w1[t*192+c];
      tv[t] = fmaxf(acc, 0.f);
    }
    __syncthreads();
    float z = 0.f;
    #pragma unroll
    for (int r=0;r<12;r++) z += tv[r]*w2[t*12+r];
    y[b*192+t] = 1.f/(1.f + __expf(-z));
    __syncthreads();
  }
}

// ---------------- K4: recompute x1, LN2, window-partition, write bf16 tokens (one batch) ----------------
__global__ __launch_bounds__(256) void k4_ln2win(const float* __restrict__ x,
    const float* __restrict__ m1, const float* __restrict__ r1, const float* __restrict__ y,
    const float* __restrict__ n1w, const float* __restrict__ n1b,
    const float* __restrict__ n2w, const float* __restrict__ n2b,
    short* __restrict__ xw, int b){
  __shared__ float xt[192*65];
  __shared__ float yl[192], w1l[192], b1l[192], w2l[192], b2l[192];
  __shared__ float ps[8*66];
  __shared__ float m2l[64], r2l[64];

  int win = blockIdx.x;
  int wh = win >> 5, ww = win & 31;
  int t = threadIdx.x;
  if (t < 192){
    yl[t] = y[b*192+t]; w1l[t] = n1w[t]; b1l[t] = n1b[t]; w2l[t] = n2w[t]; b2l[t] = n2b[t];
  }
  __syncthreads();

  int tok = t & 63, csub = t >> 6;
  int wi = tok >> 3, wj = tok & 7;
  int p = (wh*8 + wi)*256 + ww*8 + wj;
  const float* xb = x + (long)b*192*65536 + p;
  float sm = m1[b*65536 + p], sr = r1[b*65536 + p];

  #pragma unroll 4
  for (int cb=0; cb<48; cb++){
    int c = cb*4 + csub;
    float v = xb[(long)c*65536];
    float x1 = ((v - sm)*sr*w1l[c] + b1l[c]) * yl[c] * RSC + v;
    xt[c*65 + tok] = x1;
  }
  __syncthreads();
  float s = 0.f, q = 0.f;
  #pragma unroll 8
  for (int k=0;k<48;k++){
    float v = xt[(csub*48 + k)*65 + tok];
    s += v; q += v*v;
  }
  ps[csub*66 + tok] = s;
  ps[(4+csub)*66 + tok] = q;
  __syncthreads();
  if (t < 64){
    float ss = ps[t] + ps[66+t] + ps[2*66+t] + ps[3*66+t];
    float qq = ps[4*66+t] + ps[5*66+t] + ps[6*66+t] + ps[7*66+t];
    float mean = ss*(1.f/192.f);
    float var  = qq*(1.f/192.f) - mean*mean;
    m2l[t] = mean; r2l[t] = rsqrtf(var + 1e-5f);
  }
  __syncthreads();
  int tok2 = t >> 2, seg = (t & 3)*48;
  long obase = ((long)win*64 + tok2)*192 + seg;
  float mm = m2l[tok2], rr = r2l[tok2];
  #pragma unroll
  for (int ch=0; ch<6; ch++){
    bf16x8 vec;
    #pragma unroll
    for (int e=0;e<8;e++){
      int c = seg + ch*8 + e;
      float v = (xt[c*65 + tok2] - mm)*rr*w2l[c] + b2l[c];
      vec[e] = f2bf(v);
    }
    *(bf16x8*)&xw[obase + ch*8] = vec;
  }
}

// ---------------- GEMM: out[M,N](bf16) = A[M,K](bf16) @ W[N,K]^T (+bias)(+gelu) ----------------
// BK=64, 2 barriers / 64-K (halved vs BK=32). T2 XOR swizzle applied BOTH sides:
// staging pre-swizzles the GLOBAL source 16B-slot (gload_lds writes LDS linearly),
// ds_read XORs the slot with (row&7)  ->  2-way bank aliasing (free) instead of 16-way.
// Es (epilogue staging) overlays As/Bs: safe, first Es write is after the final barrier.
__global__ __launch_bounds__(256) void gemm_bt(
    const short* __restrict__ A, const short* __restrict__ Bw,
    const float* __restrict__ bias, short* __restrict__ out,
    int M, int N, int K, int epi){
  __shared__ short U[18432];          // 36 KB: As[0,8192) Bs[8192,16384) ; Es overlays [0,18432)
  short* As = U;
  short* Bs = U + 8192;
  short* Es = U;

  unsigned flat = blockIdx.y * gridDim.x + blockIdx.x;
  unsigned tot  = gridDim.x * gridDim.y;
  unsigned id2  = (flat & 7u) * (tot >> 3) + (flat >> 3);   // XCD-contiguous slabs
  int bx = id2 % gridDim.x;
  int by = id2 / gridDim.x;

  int tid = threadIdx.x;
  int lane = tid & 63;
  int wid = __builtin_amdgcn_readfirstlane(tid >> 6);
  int g = lane >> 4, a = lane & 15;
  int wr = (wid >> 1) * 64;
  int wc = (wid & 1) * 64;

  long row0 = (long)by * 128;
  int  col0 = bx * 128;

  const f32x4 zz = {0.f,0.f,0.f,0.f};
  f32x4 acc[4][4];
  #pragma unroll
  for (int i=0;i<4;i++)
    #pragma unroll
    for (int j=0;j<4;j++) acc[i][j] = zz;

  // staging: chunk c covers rows (wid*4+c)*8 + (lane>>3); 8 lanes/row, 8B... 16B each.
  // LDS[row][slot] holds global slot (slot ^ (row&7)); here row&7 == lane>>3.
  int srow = lane >> 3;                       // 0..7
  int scol = ((lane & 7) ^ srow) * 8;         // pre-swizzled global 16B-slot
  const short* ga = A  + (row0 + wid*32 + srow) * (long)K + scol;
  const short* gb = Bw + ((long)(col0 + wid*32 + srow)) * K + scol;
  short* la = &As[wid*2048];                  // + c*512 shorts (1KB chunks), lane*16B implied
  short* lb = &Bs[wid*2048];

  for (int k0 = 0; k0 < K; k0 += 64){
    #pragma unroll
    for (int c=0;c<4;c++){
      gload16(ga + k0 + c*8*(long)K, la + c*512);
      gload16(gb + k0 + c*8*(long)K, lb + c*512);
    }
    __syncthreads();
    #pragma unroll
    for (int ks=0; ks<2; ks++){
      bf16x8 af[4], bfg[4];
      #pragma unroll
      for (int t=0;t<4;t++){
        int rowA = wr + t*16 + a;
        af[t]  = *(const bf16x8*)&As[rowA*64 + ((((ks<<2)|g) ^ (rowA&7))<<3)];
        int rowB = wc + t*16 + a;
        bfg[t] = *(const bf16x8*)&Bs[rowB*64 + ((((ks<<2)|g) ^ (rowB&7))<<3)];
      }
      #pragma unroll
      for (int i=0;i<4;i++)
        #pragma unroll
        for (int j=0;j<4;j++)
          acc[i][j] = __builtin_amdgcn_mfma_f32_16x16x32_bf16(af[i], bfg[j], acc[i][j], 0, 0, 0);
    }
    __syncthreads();
  }

  float bv[4];
  #pragma unroll
  for (int j=0;j<4;j++){
    int cA = col0 + wc + j*16 + a;
    bv[j] = (epi >= 1) ? bias[cA < N ? cA : 0] : 0.f;
  }
  short* es = &Es[wid*64*72];
  #pragma unroll
  for (int i=0;i<4;i++)
    #pragma unroll
    for (int j=0;j<4;j++)
      #pragma unroll
      for (int r=0;r<4;r++){
        float v = acc[i][j][r] + bv[j];
        if (epi == 2) v = 0.5f*v*(1.f + erff(v*0.70710678118f));
        es[(i*16 + g*4 + r)*72 + j*16 + a] = f2bf(v);
      }
  // wave-private LDS region: ds_write->ds_read ordered via lgkmcnt within the wave
  if (col0 + wc < N){
    long ob = (row0 + wr + lane) * (long)N + col0 + wc;
    #pragma unroll
    for (int ch=0; ch<8; ch++)
      *(uint4*)&out[ob + ch*8] = *(const uint4*)&es[lane*72 + ch*8];
  }
}

// ---------------- window attention: one wave per (window, head) ----------------
__global__ __launch_bounds__(64) void attn_kernel(const short* __restrict__ qkv,
    const float* __restrict__ biasFrag, short* __restrict__ attOut){
  __shared__ short vlds[64*36];
  __shared__ short plds[64*72];
  __shared__ short olds[64*40];

  unsigned flat = blockIdx.x;
  unsigned tot  = gridDim.x;
  unsigned id2  = (flat & 7u) * (tot >> 3) + (flat >> 3);
  int win = id2 / 6, h = id2 % 6;
  int lane = threadIdx.x;
  int g = lane >> 4, a = lane & 15;
  long base = (long)win * 64 * 576;
  const short* qp = qkv + base + h*32;
  const short* kp = qkv + base + 192 + h*32;
  const short* vp = qkv + base + 384 + h*32;

  #pragma unroll
  for (int it=0; it<8; it++){
    int idx = it*64 + lane;
    int m = idx >> 3, ch = idx & 7;
    *(uint2*)&vlds[m*36 + ch*4] = *(const uint2*)&vp[(long)m*576 + ch*4];
  }

  bf16x8 qf[4], kf[4];
  #pragma unroll
  for (int t=0;t<4;t++) qf[t] = *(const bf16x8*)&qp[(t*16+a)*576 + g*8];
  #pragma unroll
  for (int t=0;t<4;t++) kf[t] = *(const bf16x8*)&kp[(t*16+a)*576 + g*8];

  const f32x4 zz = {0.f,0.f,0.f,0.f};
  f32x4 s[4][4];
  #pragma unroll
  for (int i=0;i<4;i++)
    #pragma unroll
    for (int j=0;j<4;j++)
      s[i][j] = __builtin_amdgcn_mfma_f32_16x16x32_bf16(qf[i], kf[j], zz, 0, 0, 0);

  const float scale = 0.17677669529663687f;
  #pragma unroll
  for (int i=0;i<4;i++)
    #pragma unroll
    for (int j=0;j<4;j++){
      f32x4 bv = *(const f32x4*)&biasFrag[(((h*16 + i*4 + j)*64) + lane)*4];
      #pragma unroll
      for (int r=0;r<4;r++) s[i][j][r] = s[i][j][r]*scale + bv[r];
    }

  #pragma unroll
  for (int i=0;i<4;i++){
    #pragma unroll
    for (int r=0;r<4;r++){
      float mx = fmaxf(fmaxf(s[i][0][r], s[i][1][r]), fmaxf(s[i][2][r], s[i][3][r]));
      mx = fmaxf(mx, __shfl_xor(mx, 1, 64));
      mx = fmaxf(mx, __shfl_xor(mx, 2, 64));
      mx = fmaxf(mx, __shfl_xor(mx, 4, 64));
      mx = fmaxf(mx, __shfl_xor(mx, 8, 64));
      float e0 = __expf(s[i][0][r]-mx), e1 = __expf(s[i][1][r]-mx);
      float e2 = __expf(s[i][2][r]-mx), e3 = __expf(s[i][3][r]-mx);
      float sm = e0+e1+e2+e3;
      sm += __shfl_xor(sm, 1, 64); sm += __shfl_xor(sm, 2, 64);
      sm += __shfl_xor(sm, 4, 64); sm += __shfl_xor(sm, 8, 64);
      float inv = 1.f/sm;
      int rowl = i*16 + g*4 + r;
      plds[rowl*72 +      a] = f2bf(e0*inv);
      plds[rowl*72 + 16 + a] = f2bf(e1*inv);
      plds[rowl*72 + 32 + a] = f2bf(e2*inv);
      plds[rowl*72 + 48 + a] = f2bf(e3*inv);
    }
  }

  f32x4 o2[4][2];
  #pragma unroll
  for (int i=0;i<4;i++){ o2[i][0] = zz; o2[i][1] = zz; }
  #pragma unroll
  for (int km=0;km<2;km++){
    bf16x8 vb0, vb1;
    #pragma unroll
    for (int j=0;j<8;j++){
      int m = km*32 + g*8 + j;
      vb0[j] = vlds[m*36 + a];
      vb1[j] = vlds[m*36 + 16 + a];
    }
    #pragma unroll
    for (int oi=0;oi<4;oi++){
      bf16x8 pa = *(const bf16x8*)&plds[(oi*16 + a)*72 + km*32 + g*8];
      o2[oi][0] = __builtin_amdgcn_mfma_f32_16x16x32_bf16(pa, vb0, o2[oi][0], 0, 0, 0);
      o2[oi][1] = __builtin_amdgcn_mfma_f32_16x16x32_bf16(pa, vb1, o2[oi][1], 0, 0, 0);
    }
  }

  #pragma unroll
  for (int oi=0;oi<4;oi++)
    #pragma unroll
    for (int oj=0;oj<2;oj++)
      #pragma unroll
      for (int r=0;r<4;r++)
        olds[(oi*16 + g*4 + r)*40 + oj*16 + a] = f2bf(o2[oi][oj][r]);
  long ob = ((long)win*64 + lane)*192 + h*32;
  #pragma unroll
  for (int ch=0;ch<4;ch++)
    *(uint4*)&attOut[ob + ch*8] = *(const uint4*)&olds[lane*40 + ch*8];
}

// ---------------- LN3: 16 lanes per token ----------------
__global__ __launch_bounds__(256) void k_ln3(const short* __restrict__ po,
    const float* __restrict__ n3w, const float* __restrict__ n3b, short* __restrict__ oln){
  int t = threadIdx.x;
  int lane = t & 63, wv = t >> 6;
  int tok = blockIdx.x*16 + wv*4 + (lane >> 4);
  int sub = lane & 15;
  long base = (long)tok*192 + sub*12;
  const short* row = po + base;
  unsigned d[6];
  #pragma unroll
  for (int k=0;k<6;k++) d[k] = *(const unsigned*)&row[k*2];
  float v[12];
  #pragma unroll
  for (int k=0;k<6;k++){
    v[2*k]   = bf2f((short)(d[k] & 0xffffu));
    v[2*k+1] = bf2f((short)(d[k] >> 16));
  }
  float s = 0.f, q = 0.f;
  #pragma unroll
  for (int e=0;e<12;e++){ s += v[e]; q += v[e]*v[e]; }
  s += __shfl_xor(s, 1, 64); s += __shfl_xor(s, 2, 64);
  s += __shfl_xor(s, 4, 64); s += __shfl_xor(s, 8, 64);
  q += __shfl_xor(q, 1, 64); q += __shfl_xor(q, 2, 64);
  q += __shfl_xor(q, 4, 64); q += __shfl_xor(q, 8, 64);
  float mean = s*(1.f/192.f);
  float var  = q*(1.f/192.f) - mean*mean;
  float r = rsqrtf(var + 1e-5f);
  short* orow = oln + base;
  #pragma unroll
  for (int k=0;k<6;k++){
    int c0 = sub*12 + 2*k;
    float a0 = (v[2*k]   - mean)*r*n3w[c0]   + n3b[c0];
    float a1 = (v[2*k+1] - mean)*r*n3w[c0+1] + n3b[c0+1];
    unsigned o = (unsigned)(unsigned short)f2bf(a0) | ((unsigned)(unsigned short)f2bf(a1) << 16);
    *(unsigned*)&orow[k*2] = o;
  }
}

// ---------------- final: LDS-transposed residual merge (one batch) ----------------
__global__ __launch_bounds__(256) void k8_final(const float* __restrict__ x,
    const float* __restrict__ m1, const float* __restrict__ r1, const float* __restrict__ y,
    const float* __restrict__ n1w, const float* __restrict__ n1b,
    const short* __restrict__ oln, const short* __restrict__ f2,
    float* __restrict__ out, int b){
  __shared__ short so[256*36];     // [w][32ch], pad 4 shorts (72B rows)
  __shared__ short sf[256*36];
  __shared__ float smm[256], srr[256];

  int row = blockIdx.x;            // image row = wh*8 + wi
  int wh = row >> 3, wi = row & 7;
  int c0 = blockIdx.y * 32;
  int t  = threadIdx.x;

  smm[t] = m1[b*65536 + row*256 + t];
  srr[t] = r1[b*65536 + row*256 + t];

  int rsub = t >> 3;               // 0..31
  int lw   = t & 7;                // 0..7
  #pragma unroll
  for (int pass=0; pass<8; pass++){
    int rw  = pass*32 + rsub;
    int tok = wh*2048 + (rw>>3)*64 + wi*8 + (rw&7);
    long gi = (long)tok*192 + c0 + lw*4;
    *(uint2*)&so[rw*36 + lw*4] = *(const uint2*)&oln[gi];
    *(uint2*)&sf[rw*36 + lw*4] = *(const uint2*)&f2[gi];
  }
  __syncthreads();

  float mm = smm[t], rr = srr[t];
  long xbase = ((long)b*192 + c0)*65536 + row*256 + t;
  #pragma unroll 4
  for (int ci=0; ci<32; ci++){
    int c = c0 + ci;
    float xv = x[xbase + (long)ci*65536];
    float ov = bf2f(so[t*36 + ci]);
    float fv = bf2f(sf[t*36 + ci]);
    float x1 = ((xv - mm)*rr*n1w[c] + n1b[c]) * y[b*192 + c] * RSC + xv;
    out[xbase + (long)ci*65536] = (ov + fv*RSC)*RSC + x1;
  }
}

extern "C" void kernel_launch(void* const* d_in, const int* in_sizes, int n_in,
                              void* d_out, int out_size, void* d_ws, size_t ws_size,
                              hipStream_t stream){
  const float* x     = (const float*)d_in[0];
  const float* n1w   = (const float*)d_in[1];
  const float* n1b   = (const float*)d_in[2];
  const float* n2w   = (const float*)d_in[3];
  const float* n2b   = (const float*)d_in[4];
  const float* n3w   = (const float*)d_in[5];
  const float* n3b   = (const float*)d_in[6];
  const float* caw1  = (const float*)d_in[7];
  const float* caw2  = (const float*)d_in[8];
  const float* qkvw  = (const float*)d_in[9];
  const float* projw = (const float*)d_in[10];
  const float* projb = (const float*)d_in[11];
  const float* rpb   = (const float*)d_in[12];
  const float* fw1   = (const float*)d_in[13];
  const float* fb1   = (const float*)d_in[14];
  const float* fw2   = (const float*)d_in[15];
  const float* fb2   = (const float*)d_in[16];
  float* out = (float*)d_out;
  char* ws = (char*)d_ws;

  size_t off = 0;
  auto alloc = [&](size_t b){ size_t r = off; off += (b + 255) & ~(size_t)255; return r; };
  size_t oWQ  = alloc(640UL*192*2);
  size_t oWP  = alloc(256UL*192*2);
  size_t oWF1 = alloc(768UL*192*2);
  size_t oWF2 = alloc(256UL*768*2);
  size_t oBF  = alloc(96UL*64*4*4);
  size_t oPOOL= alloc(768*4 + 256);
  size_t oY   = alloc(768*4);
  size_t oM   = alloc(262144UL*4);
  size_t oR   = alloc(262144UL*4);
  size_t oA   = alloc(65536UL*192*2);
  size_t oB   = alloc(65536UL*576*2);
  size_t oC   = alloc(65536UL*768*2);

  short* WQ  = (short*)(ws + oWQ);
  short* WP  = (short*)(ws + oWP);
  short* WF1 = (short*)(ws + oWF1);
  short* WF2 = (short*)(ws + oWF2);
  float* BFr = (float*)(ws + oBF);
  float* POOL= (float*)(ws + oPOOL);
  float* M1  = POOL + 768;
  float* Y   = (float*)(ws + oY);
  float* Ms  = (float*)(ws + oM);
  float* Rs  = (float*)(ws + oR);
  short* XW  = (short*)(ws + oA);
  short* ATT = XW;
  short* OLN = XW;
  short* QKV = (short*)(ws + oB);
  short* PO  = QKV;
  short* F2  = QKV;
  short* Hb  = (short*)(ws + oC);

  hipMemsetAsync(ws + oPOOL, 0, 768*4 + 16, stream);

  cvt_all<<<dim3(144, 4), 256, 0, stream>>>(qkvw, WQ, 110592, projw, WP, 36864,
                                            fw1, WF1, 147456, fw2, WF2, 147456);
  k_biasfrag<<<96, 64, 0, stream>>>(rpb, BFr);

  k12_ln1pool<<<1024, 256, 0, stream>>>(x, Ms, Rs, M1, POOL);
  k3_se<<<1, 192, 0, stream>>>(POOL, M1, n1w, n1b, caw1, caw2, Y);

  for (int b = 0; b < 4; b++){
    k4_ln2win<<<1024, 256, 0, stream>>>(x, Ms, Rs, Y, n1w, n1b, n2w, n2b, XW, b);
    gemm_bt<<<dim3(5, 512), 256, 0, stream>>>(XW, WQ, nullptr, QKV, 65536, 576, 192, 0);
    attn_kernel<<<6144, 64, 0, stream>>>(QKV, BFr, ATT);
    gemm_bt<<<dim3(2, 512), 256, 0, stream>>>(ATT, WP, projb, PO, 65536, 192, 192, 1);
    k_ln3<<<4096, 256, 0, stream>>>(PO, n3w, n3b, OLN);
    gemm_bt<<<dim3(6, 512), 256, 0, stream>>>(OLN, WF1, fb1, Hb, 65536, 768, 192, 2);
    gemm_bt<<<dim3(2, 512), 256, 0, stream>>>(Hb, WF2, fb2, F2, 65536, 192, 768, 1);
    k8_final<<<dim3(256, 6), 256, 0, stream>>>(x, Ms, Rs, Y, n1w, n1b, OLN, F2, out, b);
  }
}